// Round 2
// baseline (183.505 us; speedup 1.0000x reference)
//
#include <hip/hip_runtime.h>
#include <cstddef>

namespace {
constexpr int cB = 64, cN = 34, cF = 16, cT = 96, cK = 3, cO = 64;
constexpr int NP = 36;    // padded row stride for 34x34 fp32 matrices
constexpr int HR = 48;    // H rows padded to 3 m-tiles of 16
constexpr int HCOL = 104; // H col stride (bf16): 208B = 52 dwords -> conflict-free frag reads
constexpr float cEPS = 1e-8f;

typedef __attribute__((ext_vector_type(8))) short bf16x8;
typedef __attribute__((ext_vector_type(4))) float f32x4;

__device__ inline short f2bf(float v) {  // round-to-nearest-even f32 -> bf16 bits
    union { float f; unsigned u; } x; x.f = v;
    unsigned r = x.u + 0x7fffu + ((x.u >> 16) & 1u);
    return (short)(r >> 16);
}
}

// ---------------- softmax over axis=2 (i) of st_attention (B,K,N,N) ----------------
__global__ __launch_bounds__(256) void att_softmax_k(const float* __restrict__ st,
                                                     float* __restrict__ att) {
    int idx = blockIdx.x * blockDim.x + threadIdx.x;
    if (idx >= cB * cK * cN) return;
    int j = idx % cN;
    int bk = idx / cN;
    const float* base = st + (size_t)bk * cN * cN + j;
    float v[cN];
    float m = -3.402823466e38f;
#pragma unroll
    for (int i = 0; i < cN; ++i) { v[i] = base[(size_t)i * cN]; m = fmaxf(m, v[i]); }
    float s = 0.f;
#pragma unroll
    for (int i = 0; i < cN; ++i) { v[i] = __expf(v[i] - m); s += v[i]; }
    float inv = 1.f / s;
    float* ob = att + (size_t)bk * cN * cN + j;
#pragma unroll
    for (int i = 0; i < cN; ++i) ob[(size_t)i * cN] = v[i] * inv;
}

// ---------------- main: one block per (b,t) ----------------
__global__ __launch_bounds__(256, 5) void cheb_main_k(
    const float* __restrict__ x,      // (B,N,F,T)
    const float* __restrict__ att,    // (B,K,N,N) softmaxed
    const float* __restrict__ pos,    // (N,2)
    const float* __restrict__ dist,   // (N,N)
    const float* __restrict__ Th,     // (K,F,O)
    const float* __restrict__ ThL,    // (K,F,O)
    float* __restrict__ out)          // (B,N,O,T)
{
    __shared__ float s_gs[cN][cF];
    __shared__ float s_posv[cN][2];
    __shared__ float s_vn[cN], s_pn[cN], s_d0[cN], s_di1[cN], s_di2[cN];
    __shared__ float s_M1[cN][NP];  // L1  -> scaled by att1
    __shared__ float s_M2[cN][NP];  // A, then C1=2L1^2-I -> scaled by att2
    __shared__ float s_M3[cN][NP];  // L2  -> scaled by att1
    __shared__ float s_M4[cN][NP];  // C2=2L2^2-I -> scaled by att2
    __shared__ __align__(16) unsigned short s_H[HR][HCOL];  // bf16 H, zero-padded

    auto& s_A = s_M2;  // adjacency lives in M2 until C1 overwrites it

    const int tid = threadIdx.x;
    const int lane = tid & 63;
    const int w = tid >> 6;                 // wave id = o-block
    const int ocol = (w << 4) + (lane & 15);
    const int kb = (lane >> 4) * 8;         // per-lane k-chunk base within a 32-k step

    // XCD swizzle: consecutive logical (b,t) cluster on one XCD for L2 locality
    const unsigned g = blockIdx.x;
    const unsigned lin = (g & 7u) * (cB * cT / 8) + (g >> 3);
    const int b = lin / cT, t = lin % cT;

    // ---- B-fragments: Theta-concat columns (c = p*16+f; p0 = Th0+ThL0 merged) ----
    bf16x8 bfr[3];
#pragma unroll
    for (int s = 0; s < 3; ++s) {
#pragma unroll
        for (int j = 0; j < 8; ++j) {
            int cc = 32 * s + kb + j;
            float v = 0.f;
            if (cc < 80) {
                int p = cc >> 4, f = cc & 15;
                if (p == 0)      v = Th[f * cO + ocol] + ThL[f * cO + ocol];
                else if (p == 1) v = Th[(cF + f) * cO + ocol];
                else if (p == 2) v = Th[(2 * cF + f) * cO + ocol];
                else if (p == 3) v = ThL[(cF + f) * cO + ocol];
                else             v = ThL[(2 * cF + f) * cO + ocol];
            }
            bfr[s][j] = f2bf(v);
        }
    }

    // ---- zero H (covers m-pad rows 34..47 and k-pad cols 80..95) ----
    for (int i = tid; i < HR * HCOL / 2; i += 256) ((unsigned*)s_H)[i] = 0u;

    // ---- stage gs = x[b,:,:,t] and position ----
    for (int idx = tid; idx < cN * cF; idx += 256) {
        int n = idx >> 4, f = idx & 15;
        s_gs[n][f] = x[(((size_t)b * cN + n) * cF + f) * cT + t];
    }
    if (tid < cN * 2) ((float*)s_posv)[tid] = pos[tid];
    __syncthreads();

    // ---- vn, pn, att0 diagonal ----
    if (tid < cN) {
        float a = s_gs[tid][1], c2 = s_gs[tid][2];
        s_vn[tid] = sqrtf(a * a + c2 * c2);
    } else if (tid >= 64 && tid < 64 + cN) {
        int m = tid - 64;
        float a = s_posv[m][0], c2 = s_posv[m][1];
        s_pn[m] = sqrtf(a * a + c2 * c2);
    } else if (tid >= 128 && tid < 128 + cN) {
        int j = tid - 128;
        s_d0[j] = att[((size_t)b * cK) * cN * cN + j * cN + j];
    }
    __syncthreads();

    // ---- adjacency A (Frobenius normalization skipped: L is scale-invariant) ----
    for (int idx = tid; idx < cN * cN; idx += 256) {
        int i = idx / cN, m = idx - i * cN;
        float vn = s_vn[i];
        float dotv = s_gs[i][1] * s_posv[m][0] + s_gs[i][2] * s_posv[m][1];
        float cosv = dotv / (fmaxf(vn, cEPS) * fmaxf(s_pn[m], cEPS));
        cosv = fmaxf(cosv, 0.f);
        s_A[i][m] = cosv * vn / dist[i * cN + m];
    }
    __syncthreads();

    // ---- degree row/col sums -> dinv ----
    if (tid < cN) {
        float s = 0.f;
#pragma unroll
        for (int m = 0; m < cN; ++m) s += s_A[tid][m];
        s_di1[tid] = (s > 0.f) ? rsqrtf(fmaxf(s, 1e-12f)) : 0.f;
    } else if (tid >= 64 && tid < 64 + cN) {
        int j = tid - 64;
        float s = 0.f;
#pragma unroll
        for (int i = 0; i < cN; ++i) s += s_A[i][j];
        s_di2[j] = (s > 0.f) ? rsqrtf(fmaxf(s, 1e-12f)) : 0.f;
    }
    __syncthreads();

    // ---- L1 = I - d1 A d1 ; L2 = I - d2 A^T d2 ----
    for (int idx = tid; idx < cN * cN; idx += 256) {
        int i = idx / cN, j = idx - i * cN;
        float a = s_A[i][j], at = s_A[j][i];
        float diag = (i == j) ? 1.f : 0.f;
        s_M1[i][j] = diag - s_di1[i] * a * s_di1[j];
        s_M3[i][j] = diag - s_di2[i] * at * s_di2[j];
    }
    __syncthreads();

    // ---- C1 = 2 L1@L1 - I (into M2, A is dead) ; C2 = 2 L2@L2 - I ----
    for (int idx = tid; idx < cN * 9; idx += 256) {
        int i = idx / 9, j4 = idx - i * 9;
        int j0 = j4 * 4;
        float4 a1 = make_float4(0.f, 0.f, 0.f, 0.f);
        float4 a2 = make_float4(0.f, 0.f, 0.f, 0.f);
        for (int q = 0; q < cN; ++q) {
            float l1 = s_M1[i][q];
            float4 r1 = *(const float4*)&s_M1[q][j0];
            a1.x = fmaf(l1, r1.x, a1.x); a1.y = fmaf(l1, r1.y, a1.y);
            a1.z = fmaf(l1, r1.z, a1.z); a1.w = fmaf(l1, r1.w, a1.w);
            float l2 = s_M3[i][q];
            float4 r2 = *(const float4*)&s_M3[q][j0];
            a2.x = fmaf(l2, r2.x, a2.x); a2.y = fmaf(l2, r2.y, a2.y);
            a2.z = fmaf(l2, r2.z, a2.z); a2.w = fmaf(l2, r2.w, a2.w);
        }
        float4 o1, o2;
        o1.x = 2.f * a1.x - ((i == j0 + 0) ? 1.f : 0.f);
        o1.y = 2.f * a1.y - ((i == j0 + 1) ? 1.f : 0.f);
        o1.z = 2.f * a1.z - ((i == j0 + 2) ? 1.f : 0.f);
        o1.w = 2.f * a1.w - ((i == j0 + 3) ? 1.f : 0.f);
        o2.x = 2.f * a2.x - ((i == j0 + 0) ? 1.f : 0.f);
        o2.y = 2.f * a2.y - ((i == j0 + 1) ? 1.f : 0.f);
        o2.z = 2.f * a2.z - ((i == j0 + 2) ? 1.f : 0.f);
        o2.w = 2.f * a2.w - ((i == j0 + 3) ? 1.f : 0.f);
        *(float4*)&s_M2[i][j0] = o1;
        *(float4*)&s_M4[i][j0] = o2;
    }
    __syncthreads();

    // ---- scale cheb matrices by attention in place ----
    const float* att1 = att + ((size_t)b * cK + 1) * cN * cN;
    const float* att2 = att + ((size_t)b * cK + 2) * cN * cN;
    for (int idx = tid; idx < cN * cN; idx += 256) {
        int i = idx / cN, j = idx - i * cN;
        float a1 = att1[idx], a2 = att2[idx];
        s_M1[i][j] *= a1;
        s_M3[i][j] *= a1;
        s_M2[i][j] *= a2;
        s_M4[i][j] *= a2;
    }
    __syncthreads();

    // ---- H[j][p*16+f] (bf16): p0 diag term, p1..p4 = M^T @ gs ----
    for (int idx = tid; idx < cN * 20; idx += 256) {
        int j = idx / 20, c4 = idx - j * 20;
        int p = c4 >> 2, f0 = (c4 & 3) << 2;
        float r0, r1, r2, r3;
        if (p == 0) {
            float d = s_d0[j];
            float4 gv = *(const float4*)&s_gs[j][f0];
            r0 = d * gv.x; r1 = d * gv.y; r2 = d * gv.z; r3 = d * gv.w;
        } else {
            const float (*M)[NP] = (p == 1) ? s_M1 : (p == 2) ? s_M2
                                 : (p == 3) ? s_M3 : s_M4;
            float4 acc = make_float4(0.f, 0.f, 0.f, 0.f);
            for (int i2 = 0; i2 < cN; ++i2) {
                float mm = M[i2][j];
                float4 gv = *(const float4*)&s_gs[i2][f0];
                acc.x = fmaf(mm, gv.x, acc.x); acc.y = fmaf(mm, gv.y, acc.y);
                acc.z = fmaf(mm, gv.z, acc.z); acc.w = fmaf(mm, gv.w, acc.w);
            }
            r0 = acc.x; r1 = acc.y; r2 = acc.z; r3 = acc.w;
        }
        short4 pk;
        pk.x = f2bf(r0); pk.y = f2bf(r1); pk.z = f2bf(r2); pk.w = f2bf(r3);
        *(short4*)&s_H[j][(p << 4) + f0] = pk;
    }
    __syncthreads();

    // ---- final: out tile (48x16 per wave) = H @ Thcat via bf16 MFMA ----
    f32x4 acc[3];
#pragma unroll
    for (int m = 0; m < 3; ++m) acc[m] = (f32x4){0.f, 0.f, 0.f, 0.f};
#pragma unroll
    for (int s = 0; s < 3; ++s) {
#pragma unroll
        for (int m = 0; m < 3; ++m) {
            bf16x8 a = *(const bf16x8*)&s_H[m * 16 + (lane & 15)][kb + 32 * s];
            acc[m] = __builtin_amdgcn_mfma_f32_16x16x32_bf16(a, bfr[s], acc[m], 0, 0, 0);
        }
    }
    const int r0 = (lane >> 4) * 4;
#pragma unroll
    for (int m = 0; m < 3; ++m) {
#pragma unroll
        for (int r = 0; r < 4; ++r) {
            int j = m * 16 + r0 + r;
            if (j < cN)
                out[(((size_t)b * cN + j) * cO + ocol) * cT + t] = fmaxf(acc[m][r], 0.f);
        }
    }
}

extern "C" void kernel_launch(void* const* d_in, const int* in_sizes, int n_in,
                              void* d_out, int out_size, void* d_ws, size_t ws_size,
                              hipStream_t stream) {
    const float* x    = (const float*)d_in[0];
    const float* st   = (const float*)d_in[1];
    const float* pos  = (const float*)d_in[2];
    const float* dist = (const float*)d_in[3];
    const float* Th   = (const float*)d_in[4];
    const float* ThL  = (const float*)d_in[5];
    float* out = (float*)d_out;
    float* att = (float*)d_ws;  // B*K*N*N floats = 888 KB

    att_softmax_k<<<(cB * cK * cN + 255) / 256, 256, 0, stream>>>(st, att);
    cheb_main_k<<<cB * cT, 256, 0, stream>>>(x, att, pos, dist, Th, ThL, out);
}

// Round 3
// 116.608 us; speedup vs baseline: 1.5737x; 1.5737x over previous
//
#include <hip/hip_runtime.h>
#include <cstddef>

namespace {
constexpr int cB = 64, cN = 34, cF = 16, cT = 96, cK = 3, cO = 64;
constexpr int NP = 36;    // padded row stride for 34x34 fp32 matrices
constexpr int TT = 4;     // t-tile per block
constexpr int HR = 144;   // H rows: 34*4=136 padded to 9 m-tiles of 16
constexpr int HCOL = 104; // H col stride (bf16): 208B = 13*16B, 2-way-free bank pattern
constexpr float cEPS = 1e-8f;

typedef __attribute__((ext_vector_type(8))) short bf16x8;
typedef __attribute__((ext_vector_type(4))) float f32x4;

__device__ inline short f2bf(float v) {  // round-to-nearest-even f32 -> bf16 bits
    union { float f; unsigned u; } x; x.f = v;
    unsigned r = x.u + 0x7fffu + ((x.u >> 16) & 1u);
    return (short)(r >> 16);
}
}

// ---------------- softmax over axis=2 (i) of st_attention (B,K,N,N) ----------------
__global__ __launch_bounds__(256) void att_softmax_k(const float* __restrict__ st,
                                                     float* __restrict__ att) {
    int idx = blockIdx.x * blockDim.x + threadIdx.x;
    if (idx >= cB * cK * cN) return;
    int j = idx % cN;
    int bk = idx / cN;
    const float* base = st + (size_t)bk * cN * cN + j;
    float v[cN];
    float m = -3.402823466e38f;
#pragma unroll
    for (int i = 0; i < cN; ++i) { v[i] = base[(size_t)i * cN]; m = fmaxf(m, v[i]); }
    float s = 0.f;
#pragma unroll
    for (int i = 0; i < cN; ++i) { v[i] = __expf(v[i] - m); s += v[i]; }
    float inv = 1.f / s;
    float* ob = att + (size_t)bk * cN * cN + j;
#pragma unroll
    for (int i = 0; i < cN; ++i) ob[(size_t)i * cN] = v[i] * inv;
}

// ---------------- main: one block per (b, 4-t tile) ----------------
__global__ __launch_bounds__(256, 3) void cheb_main_k(
    const float* __restrict__ x,      // (B,N,F,T)
    const float* __restrict__ att,    // (B,K,N,N) softmaxed
    const float* __restrict__ pos,    // (N,2)
    const float* __restrict__ dist,   // (N,N)
    const float* __restrict__ Th,     // (K,F,O)
    const float* __restrict__ ThL,    // (K,F,O)
    float* __restrict__ out)          // (B,N,O,T)
{
    __shared__ float s_gs[cN][cF];
    __shared__ float s_posv[cN][2];
    __shared__ float s_vn[cN], s_pn[cN], s_d0[cN], s_di1[cN], s_di2[cN];
    __shared__ float s_M1[cN][NP];  // L1  -> scaled by att1
    __shared__ float s_M2[cN][NP];  // A, then C1=2L1^2-I -> scaled by att2
    __shared__ float s_M3[cN][NP];  // L2  -> scaled by att1
    __shared__ float s_M4[cN][NP];  // C2=2L2^2-I -> scaled by att2
    __shared__ __align__(16) unsigned short s_H[HR][HCOL];  // bf16 H, rows j*4+tt

    auto& s_A = s_M2;  // adjacency lives in M2 until C1 overwrites it

    const int tid = threadIdx.x;
    const int lane = tid & 63;
    const int w = tid >> 6;                 // wave id = o-block
    const int ocol = (w << 4) + (lane & 15);
    const int kb = (lane >> 4) * 8;         // per-lane k-chunk base within a 32-k step

    // XCD swizzle: same-b tiles cluster on one XCD, consecutive t-tiles adjacent
    const unsigned g = blockIdx.x;
    const unsigned lin = (g & 7u) * (cB * (cT / TT) / 8) + (g >> 3);
    const int b = lin / (cT / TT);
    const int t0 = (lin % (cT / TT)) * TT;

    // ---- B-fragments: Theta-concat columns (c = p*16+f; p0 = Th0+ThL0 merged) ----
    bf16x8 bfr[3];
#pragma unroll
    for (int s = 0; s < 3; ++s) {
#pragma unroll
        for (int j = 0; j < 8; ++j) {
            int cc = 32 * s + kb + j;
            float v = 0.f;
            if (cc < 80) {
                int p = cc >> 4, f = cc & 15;
                if (p == 0)      v = Th[f * cO + ocol] + ThL[f * cO + ocol];
                else if (p == 1) v = Th[(cF + f) * cO + ocol];
                else if (p == 2) v = Th[(2 * cF + f) * cO + ocol];
                else if (p == 3) v = ThL[(cF + f) * cO + ocol];
                else             v = ThL[(2 * cF + f) * cO + ocol];
            }
            bfr[s][j] = f2bf(v);
        }
    }

    // ---- per-block one-time init: zero H, posv, pn, att0 diag ----
    for (int i = tid; i < HR * HCOL / 2; i += 256) ((unsigned*)s_H)[i] = 0u;
    if (tid < cN * 2) {
        ((float*)s_posv)[tid] = pos[tid];
    } else if (tid >= 128 && tid < 128 + cN) {
        int m = tid - 128;
        float a = pos[2 * m], c2 = pos[2 * m + 1];
        s_pn[m] = sqrtf(a * a + c2 * c2);
    } else if (tid >= 192 && tid < 192 + cN) {
        int j = tid - 192;
        s_d0[j] = att[((size_t)b * cK) * cN * cN + j * cN + j];
    }

    const float* att1 = att + ((size_t)b * cK + 1) * cN * cN;
    const float* att2 = att + ((size_t)b * cK + 2) * cN * cN;

    for (int tt = 0; tt < TT; ++tt) {
        const int t = t0 + tt;
        // ---- stage gs = x[b,:,:,t]; vn from global x (independent) ----
        for (int idx = tid; idx < cN * cF; idx += 256) {
            int n = idx >> 4, f = idx & 15;
            s_gs[n][f] = x[(((size_t)b * cN + n) * cF + f) * cT + t];
        }
        if (tid >= 192 && tid < 192 + cN) {
            int n = tid - 192;
            float a = x[(((size_t)b * cN + n) * cF + 1) * cT + t];
            float c2 = x[(((size_t)b * cN + n) * cF + 2) * cT + t];
            s_vn[n] = sqrtf(a * a + c2 * c2);
        }
        __syncthreads();

        // ---- adjacency A (Frobenius norm skipped: L is scale-invariant) ----
        for (int idx = tid; idx < cN * cN; idx += 256) {
            int i = idx / cN, m = idx - i * cN;
            float vn = s_vn[i];
            float dotv = s_gs[i][1] * s_posv[m][0] + s_gs[i][2] * s_posv[m][1];
            float cosv = dotv / (fmaxf(vn, cEPS) * fmaxf(s_pn[m], cEPS));
            cosv = fmaxf(cosv, 0.f);
            s_A[i][m] = cosv * vn / dist[i * cN + m];
        }
        __syncthreads();

        // ---- degree row/col sums -> dinv ----
        if (tid < cN) {
            float s = 0.f;
#pragma unroll
            for (int m = 0; m < cN; ++m) s += s_A[tid][m];
            s_di1[tid] = (s > 0.f) ? rsqrtf(fmaxf(s, 1e-12f)) : 0.f;
        } else if (tid >= 64 && tid < 64 + cN) {
            int j = tid - 64;
            float s = 0.f;
#pragma unroll
            for (int i = 0; i < cN; ++i) s += s_A[i][j];
            s_di2[j] = (s > 0.f) ? rsqrtf(fmaxf(s, 1e-12f)) : 0.f;
        }
        __syncthreads();

        // ---- L1 = I - d1 A d1 ; L2 = I - d2 A^T d2 ----
        for (int idx = tid; idx < cN * cN; idx += 256) {
            int i = idx / cN, j = idx - i * cN;
            float a = s_A[i][j], at = s_A[j][i];
            float diag = (i == j) ? 1.f : 0.f;
            s_M1[i][j] = diag - s_di1[i] * a * s_di1[j];
            s_M3[i][j] = diag - s_di2[i] * at * s_di2[j];
        }
        __syncthreads();

        // ---- C1 = 2 L1@L1 - I (into M2) ; C2 = 2 L2@L2 - I (into M4) ----
        for (int idx = tid; idx < cN * 9; idx += 256) {
            int i = idx / 9, j4 = idx - i * 9;
            int j0 = j4 * 4;
            float4 a1 = make_float4(0.f, 0.f, 0.f, 0.f);
            float4 a2 = make_float4(0.f, 0.f, 0.f, 0.f);
            for (int q = 0; q < cN; ++q) {
                float l1 = s_M1[i][q];
                float4 r1 = *(const float4*)&s_M1[q][j0];
                a1.x = fmaf(l1, r1.x, a1.x); a1.y = fmaf(l1, r1.y, a1.y);
                a1.z = fmaf(l1, r1.z, a1.z); a1.w = fmaf(l1, r1.w, a1.w);
                float l2 = s_M3[i][q];
                float4 r2 = *(const float4*)&s_M3[q][j0];
                a2.x = fmaf(l2, r2.x, a2.x); a2.y = fmaf(l2, r2.y, a2.y);
                a2.z = fmaf(l2, r2.z, a2.z); a2.w = fmaf(l2, r2.w, a2.w);
            }
            float4 o1, o2;
            o1.x = 2.f * a1.x - ((i == j0 + 0) ? 1.f : 0.f);
            o1.y = 2.f * a1.y - ((i == j0 + 1) ? 1.f : 0.f);
            o1.z = 2.f * a1.z - ((i == j0 + 2) ? 1.f : 0.f);
            o1.w = 2.f * a1.w - ((i == j0 + 3) ? 1.f : 0.f);
            o2.x = 2.f * a2.x - ((i == j0 + 0) ? 1.f : 0.f);
            o2.y = 2.f * a2.y - ((i == j0 + 1) ? 1.f : 0.f);
            o2.z = 2.f * a2.z - ((i == j0 + 2) ? 1.f : 0.f);
            o2.w = 2.f * a2.w - ((i == j0 + 3) ? 1.f : 0.f);
            *(float4*)&s_M2[i][j0] = o1;
            *(float4*)&s_M4[i][j0] = o2;
        }
        __syncthreads();

        // ---- scale cheb matrices by attention in place (att from global, L1-hot) ----
        for (int idx = tid; idx < cN * cN; idx += 256) {
            int i = idx / cN, j = idx - i * cN;
            float a1 = att1[idx], a2 = att2[idx];
            s_M1[i][j] *= a1;
            s_M3[i][j] *= a1;
            s_M2[i][j] *= a2;
            s_M4[i][j] *= a2;
        }
        __syncthreads();

        // ---- H row j*4+tt (bf16): p0 diag term, p1..p4 = M^T @ gs ----
        for (int idx = tid; idx < cN * 20; idx += 256) {
            int j = idx / 20, c4 = idx - j * 20;
            int p = c4 >> 2, f0 = (c4 & 3) << 2;
            float r0, r1, r2, r3;
            if (p == 0) {
                float d = s_d0[j];
                float4 gv = *(const float4*)&s_gs[j][f0];
                r0 = d * gv.x; r1 = d * gv.y; r2 = d * gv.z; r3 = d * gv.w;
            } else {
                const float (*M)[NP] = (p == 1) ? s_M1 : (p == 2) ? s_M2
                                     : (p == 3) ? s_M3 : s_M4;
                float4 acc = make_float4(0.f, 0.f, 0.f, 0.f);
                for (int i2 = 0; i2 < cN; ++i2) {
                    float mm = M[i2][j];
                    float4 gv = *(const float4*)&s_gs[i2][f0];
                    acc.x = fmaf(mm, gv.x, acc.x); acc.y = fmaf(mm, gv.y, acc.y);
                    acc.z = fmaf(mm, gv.z, acc.z); acc.w = fmaf(mm, gv.w, acc.w);
                }
                r0 = acc.x; r1 = acc.y; r2 = acc.z; r3 = acc.w;
            }
            short4 pk;
            pk.x = f2bf(r0); pk.y = f2bf(r1); pk.z = f2bf(r2); pk.w = f2bf(r3);
            *(short4*)&s_H[(j << 2) + tt][(p << 4) + f0] = pk;
        }
        __syncthreads();
    }

    // ---- final: (144x80) @ (80x16 per wave) via bf16 MFMA ----
    f32x4 acc[9];
#pragma unroll
    for (int m = 0; m < 9; ++m) acc[m] = (f32x4){0.f, 0.f, 0.f, 0.f};
#pragma unroll
    for (int s = 0; s < 3; ++s) {
#pragma unroll
        for (int m = 0; m < 9; ++m) {
            bf16x8 a = *(const bf16x8*)&s_H[m * 16 + (lane & 15)][kb + 32 * s];
            acc[m] = __builtin_amdgcn_mfma_f32_16x16x32_bf16(a, bfr[s], acc[m], 0, 0, 0);
        }
    }

    // ---- stores: acc[m] = out[j, ocol, t0..t0+3] -> one aligned float4 each ----
    const int q = lane >> 4;
#pragma unroll
    for (int m = 0; m < 9; ++m) {
        int j = 4 * m + q;
        if (j < cN) {
            float4 v;
            v.x = fmaxf(acc[m][0], 0.f);
            v.y = fmaxf(acc[m][1], 0.f);
            v.z = fmaxf(acc[m][2], 0.f);
            v.w = fmaxf(acc[m][3], 0.f);
            *(float4*)&out[(((size_t)b * cN + j) * cO + ocol) * cT + t0] = v;
        }
    }
}

extern "C" void kernel_launch(void* const* d_in, const int* in_sizes, int n_in,
                              void* d_out, int out_size, void* d_ws, size_t ws_size,
                              hipStream_t stream) {
    const float* x    = (const float*)d_in[0];
    const float* st   = (const float*)d_in[1];
    const float* pos  = (const float*)d_in[2];
    const float* dist = (const float*)d_in[3];
    const float* Th   = (const float*)d_in[4];
    const float* ThL  = (const float*)d_in[5];
    float* out = (float*)d_out;
    float* att = (float*)d_ws;  // B*K*N*N floats = 888 KB

    att_softmax_k<<<(cB * cK * cN + 255) / 256, 256, 0, stream>>>(st, att);
    cheb_main_k<<<cB * (cT / TT), 256, 0, stream>>>(x, att, pos, dist, Th, ThL, out);
}